// Round 2
// baseline (1495.157 us; speedup 1.0000x reference)
//
#include <hip/hip_runtime.h>
#include <hip/hip_bf16.h>
#include <cstdint>

#define GAMMA 0.1f

// ---------------- fp32 tiled GEMM: C[M,Nn] = A[M,K] @ B[K,Nn] ----------------
#define BM 64
#define BN 64
#define BK 16

__global__ __launch_bounds__(256) void gemm_f32(const float* __restrict__ A,
                                                const float* __restrict__ B,
                                                float* __restrict__ C,
                                                int M, int Nn, int K) {
    __shared__ float As[BK][BM + 1];
    __shared__ float Bs[BK][BN + 1];
    int tid = threadIdx.x;
    int m0 = blockIdx.x * BM;
    int n0 = blockIdx.y * BN;
    int tx = tid & 15, ty = tid >> 4;

    // A load mapping: each thread loads a float4 along K
    int am = tid >> 2;          // 0..63
    int ak = (tid & 3) << 2;    // 0,4,8,12
    // B load mapping: each thread loads a float4 along N
    int bk = tid >> 4;          // 0..15
    int bn = (tid & 15) << 2;   // 0..60

    float acc[4][4] = {};

    for (int k0 = 0; k0 < K; k0 += BK) {
        // load A tile (rows m0..m0+63, cols k0..k0+15)
        float4 av = make_float4(0.f, 0.f, 0.f, 0.f);
        int arow = m0 + am;
        if (arow < M)
            av = *reinterpret_cast<const float4*>(&A[(long long)arow * K + k0 + ak]);
        As[ak + 0][am] = av.x;
        As[ak + 1][am] = av.y;
        As[ak + 2][am] = av.z;
        As[ak + 3][am] = av.w;

        // load B tile (rows k0..k0+15, cols n0..n0+63)
        int brow = k0 + bk;
        float4 bv;
        if (n0 + bn + 3 < Nn) {
            bv = *reinterpret_cast<const float4*>(&B[(long long)brow * Nn + n0 + bn]);
        } else {
            float t[4] = {0.f, 0.f, 0.f, 0.f};
            #pragma unroll
            for (int j = 0; j < 4; ++j)
                if (n0 + bn + j < Nn) t[j] = B[(long long)brow * Nn + n0 + bn + j];
            bv = make_float4(t[0], t[1], t[2], t[3]);
        }
        Bs[bk][bn + 0] = bv.x;
        Bs[bk][bn + 1] = bv.y;
        Bs[bk][bn + 2] = bv.z;
        Bs[bk][bn + 3] = bv.w;

        __syncthreads();

        #pragma unroll
        for (int k = 0; k < BK; ++k) {
            float a[4], b[4];
            #pragma unroll
            for (int i = 0; i < 4; ++i) a[i] = As[k][ty * 4 + i];
            #pragma unroll
            for (int j = 0; j < 4; ++j) b[j] = Bs[k][tx * 4 + j];
            #pragma unroll
            for (int i = 0; i < 4; ++i)
                #pragma unroll
                for (int j = 0; j < 4; ++j)
                    acc[i][j] += a[i] * b[j];
        }
        __syncthreads();
    }

    #pragma unroll
    for (int i = 0; i < 4; ++i) {
        int r = m0 + ty * 4 + i;
        if (r >= M) continue;
        #pragma unroll
        for (int j = 0; j < 4; ++j) {
            int c = n0 + tx * 4 + j;
            if (c < Nn) C[(long long)r * Nn + c] = acc[i][j];
        }
    }
}

// ---------------- fused dual row-dot: s = sigmoid(X@sw+sb), dk = X@dw+db ----------------
__global__ __launch_bounds__(256) void rowdot2(const float* __restrict__ X, int K,
                                               const float* __restrict__ sw,
                                               const float* __restrict__ dw,
                                               const float* __restrict__ sb,
                                               const float* __restrict__ db,
                                               float* __restrict__ s_out,
                                               float* __restrict__ dk_out, int M) {
    int wave = (int)((blockIdx.x * (long long)blockDim.x + threadIdx.x) >> 6);
    int lane = threadIdx.x & 63;
    if (wave >= M) return;
    const float* xr = X + (long long)wave * K;
    float as = 0.f, ad = 0.f;
    for (int k = lane; k < K; k += 64) {
        float v = xr[k];
        as += v * sw[k];
        ad += v * dw[k];
    }
    #pragma unroll
    for (int off = 32; off; off >>= 1) {
        as += __shfl_down(as, off);
        ad += __shfl_down(ad, off);
    }
    if (lane == 0) {
        float sv = as + sb[0];
        s_out[wave] = 1.f / (1.f + __expf(-sv));
        dk_out[wave] = ad + db[0];
    }
}

// ---------------- SPMM scatter: Y[row[e], :] += val[e] * X[col[e], :] ----------------
template <int D>
__global__ __launch_bounds__(256) void spmm_atomic(const int* __restrict__ row,
                                                   const int* __restrict__ col,
                                                   const float* __restrict__ val,
                                                   const float* __restrict__ X,
                                                   float* __restrict__ Y, int E) {
    long long idx = (long long)blockIdx.x * blockDim.x + threadIdx.x;
    long long total = (long long)E * D;
    if (idx >= total) return;
    int e = (int)(idx / D);
    int c = (int)(idx % D);
    float v = val[e] * X[(long long)col[e] * D + c];
    atomicAdd(&Y[(long long)row[e] * D + c], v);
}

// ---------------- combine layer-1 (in place over sup buffer) ----------------
__global__ __launch_bounds__(256) void combine1_k(const float* __restrict__ hadj,
                                                  const float* __restrict__ hknn,
                                                  const float* __restrict__ sup,
                                                  const float* __restrict__ s,
                                                  const float* __restrict__ dk,
                                                  const float* __restrict__ b,
                                                  float* __restrict__ out,
                                                  int M, int D) {
    long long idx = (long long)blockIdx.x * blockDim.x + threadIdx.x;
    if (idx >= (long long)M * D) return;
    int i = (int)(idx / D);
    int j = (int)(idx % D);
    float si = s[i];
    float g = GAMMA * dk[i];
    out[idx] = si * hadj[idx] + (1.f - si) * hknn[idx] + g * sup[idx] + b[j] * (1.f + g);
}

// ---------------- combine layer-2 + log_softmax (one wave per row, C=40) ----------------
__global__ __launch_bounds__(256) void combine2_lsm(const float* __restrict__ hadj,
                                                    const float* __restrict__ hknn,
                                                    const float* __restrict__ sup,
                                                    const float* __restrict__ s,
                                                    const float* __restrict__ dk,
                                                    const float* __restrict__ b,
                                                    float* __restrict__ out, int M) {
    int wave = (int)((blockIdx.x * (long long)blockDim.x + threadIdx.x) >> 6);
    int lane = threadIdx.x & 63;
    if (wave >= M) return;
    long long base = (long long)wave * 40;
    float si = s[wave];
    float g = GAMMA * dk[wave];
    float z = -INFINITY;
    if (lane < 40)
        z = si * hadj[base + lane] + (1.f - si) * hknn[base + lane] + g * sup[base + lane] +
            b[lane] * (1.f + g);
    float m = z;
    #pragma unroll
    for (int off = 32; off; off >>= 1) m = fmaxf(m, __shfl_xor(m, off));
    float ex = (lane < 40) ? __expf(z - m) : 0.f;
    float sum = ex;
    #pragma unroll
    for (int off = 32; off; off >>= 1) sum += __shfl_xor(sum, off);
    float lse = m + __logf(sum);
    if (lane < 40) out[base + lane] = z - lse;
}

extern "C" void kernel_launch(void* const* d_in, const int* in_sizes, int n_in,
                              void* d_out, int out_size, void* d_ws, size_t ws_size,
                              hipStream_t stream) {
    const int N = 50000, F = 512, H = 128, C = 40;

    const float* fea     = (const float*)d_in[0];
    const int*   adj_row = (const int*)d_in[1];
    const int*   adj_col = (const int*)d_in[2];
    const float* adj_val = (const float*)d_in[3];
    const int*   knn_row = (const int*)d_in[4];
    const int*   knn_col = (const int*)d_in[5];
    const float* knn_val = (const float*)d_in[6];
    const float* W1      = (const float*)d_in[7];
    const float* b1      = (const float*)d_in[8];
    const float* W2      = (const float*)d_in[9];
    const float* b2      = (const float*)d_in[10];
    const float* score1  = (const float*)d_in[11];
    const float* score2  = (const float*)d_in[12];
    const float* sbias1  = (const float*)d_in[13];
    const float* sbias2  = (const float*)d_in[14];
    const float* Dk1     = (const float*)d_in[15];
    const float* Dk2     = (const float*)d_in[16];
    const float* Dbias1  = (const float*)d_in[17];
    const float* Dbias2  = (const float*)d_in[18];

    const int E  = in_sizes[1];
    const int EK = in_sizes[4];

    // output layout: [log_softmax (N*C)] [embedding (N*H)]
    float* out_lsm = (float*)d_out;
    float* emb     = out_lsm + (size_t)N * C;   // support1 / x1 stored here (in-place combine)

    // workspace: two scatter accumulators (N*H each, reused as N*C in layer 2) + gates
    float* hadj  = (float*)d_ws;
    float* hknn  = hadj + (size_t)N * H;
    float* s_buf = hknn + (size_t)N * H;
    float* dk_buf = s_buf + N;

    // ---------- layer 1 ----------
    // support1 = fea @ W1  -> emb region
    {
        dim3 grid((N + BM - 1) / BM, (H + BN - 1) / BN);
        gemm_f32<<<grid, 256, 0, stream>>>(fea, W1, emb, N, H, F);
    }
    // gates
    rowdot2<<<(N + 3) / 4, 256, 0, stream>>>(fea, F, score1, Dk1, sbias1, Dbias1,
                                             s_buf, dk_buf, N);
    // zero accumulators
    hipMemsetAsync(hadj, 0, (size_t)N * H * sizeof(float), stream);
    hipMemsetAsync(hknn, 0, (size_t)N * H * sizeof(float), stream);
    // scatter SPMMs
    {
        long long tot = (long long)E * H;
        spmm_atomic<128><<<(int)((tot + 255) / 256), 256, 0, stream>>>(adj_row, adj_col,
                                                                        adj_val, emb, hadj, E);
        tot = (long long)EK * H;
        spmm_atomic<128><<<(int)((tot + 255) / 256), 256, 0, stream>>>(knn_row, knn_col,
                                                                        knn_val, emb, hknn, EK);
    }
    // combine -> emb (in place: out[idx] depends only on inputs at idx)
    {
        long long tot = (long long)N * H;
        combine1_k<<<(int)((tot + 255) / 256), 256, 0, stream>>>(hadj, hknn, emb, s_buf,
                                                                  dk_buf, b1, emb, N, H);
    }

    // ---------- layer 2 ----------
    // support2 = emb @ W2 -> out_lsm region (in-place combine+lsm later)
    {
        dim3 grid((N + BM - 1) / BM, (C + BN - 1) / BN);
        gemm_f32<<<grid, 256, 0, stream>>>(emb, W2, out_lsm, N, C, H);
    }
    rowdot2<<<(N + 3) / 4, 256, 0, stream>>>(emb, H, score2, Dk2, sbias2, Dbias2,
                                             s_buf, dk_buf, N);
    hipMemsetAsync(hadj, 0, (size_t)N * C * sizeof(float), stream);
    hipMemsetAsync(hknn, 0, (size_t)N * C * sizeof(float), stream);
    {
        long long tot = (long long)E * C;
        spmm_atomic<40><<<(int)((tot + 255) / 256), 256, 0, stream>>>(adj_row, adj_col,
                                                                       adj_val, out_lsm, hadj, E);
        tot = (long long)EK * C;
        spmm_atomic<40><<<(int)((tot + 255) / 256), 256, 0, stream>>>(knn_row, knn_col,
                                                                       knn_val, out_lsm, hknn, EK);
    }
    combine2_lsm<<<(N + 3) / 4, 256, 0, stream>>>(hadj, hknn, out_lsm, s_buf, dk_buf,
                                                  b2, out_lsm, N);
    (void)n_in; (void)out_size; (void)ws_size; (void)b2;
}

// Round 3
// 1045.613 us; speedup vs baseline: 1.4299x; 1.4299x over previous
//
#include <hip/hip_runtime.h>
#include <hip/hip_bf16.h>
#include <cstdint>

#define GAMMA 0.1f

// ---------------- fp32 tiled GEMM: C[M,Nn] = A[M,K] @ B[K,Nn] ----------------
#define BM 64
#define BN 64
#define BK 16

__global__ __launch_bounds__(256) void gemm_f32(const float* __restrict__ A,
                                                const float* __restrict__ B,
                                                float* __restrict__ C,
                                                int M, int Nn, int K) {
    __shared__ float As[BK][BM + 1];
    __shared__ float Bs[BK][BN + 1];
    int tid = threadIdx.x;
    int m0 = blockIdx.x * BM;
    int n0 = blockIdx.y * BN;
    int tx = tid & 15, ty = tid >> 4;

    int am = tid >> 2;          // 0..63
    int ak = (tid & 3) << 2;    // 0,4,8,12
    int bk = tid >> 4;          // 0..15
    int bn = (tid & 15) << 2;   // 0..60

    float acc[4][4] = {};

    for (int k0 = 0; k0 < K; k0 += BK) {
        float4 av = make_float4(0.f, 0.f, 0.f, 0.f);
        int arow = m0 + am;
        if (arow < M)
            av = *reinterpret_cast<const float4*>(&A[(long long)arow * K + k0 + ak]);
        As[ak + 0][am] = av.x;
        As[ak + 1][am] = av.y;
        As[ak + 2][am] = av.z;
        As[ak + 3][am] = av.w;

        int brow = k0 + bk;
        float4 bv;
        if (n0 + bn + 3 < Nn) {
            bv = *reinterpret_cast<const float4*>(&B[(long long)brow * Nn + n0 + bn]);
        } else {
            float t[4] = {0.f, 0.f, 0.f, 0.f};
            #pragma unroll
            for (int j = 0; j < 4; ++j)
                if (n0 + bn + j < Nn) t[j] = B[(long long)brow * Nn + n0 + bn + j];
            bv = make_float4(t[0], t[1], t[2], t[3]);
        }
        Bs[bk][bn + 0] = bv.x;
        Bs[bk][bn + 1] = bv.y;
        Bs[bk][bn + 2] = bv.z;
        Bs[bk][bn + 3] = bv.w;

        __syncthreads();

        #pragma unroll
        for (int k = 0; k < BK; ++k) {
            float a[4], b[4];
            #pragma unroll
            for (int i = 0; i < 4; ++i) a[i] = As[k][ty * 4 + i];
            #pragma unroll
            for (int j = 0; j < 4; ++j) b[j] = Bs[k][tx * 4 + j];
            #pragma unroll
            for (int i = 0; i < 4; ++i)
                #pragma unroll
                for (int j = 0; j < 4; ++j)
                    acc[i][j] += a[i] * b[j];
        }
        __syncthreads();
    }

    #pragma unroll
    for (int i = 0; i < 4; ++i) {
        int r = m0 + ty * 4 + i;
        if (r >= M) continue;
        #pragma unroll
        for (int j = 0; j < 4; ++j) {
            int c = n0 + tx * 4 + j;
            if (c < Nn) C[(long long)r * Nn + c] = acc[i][j];
        }
    }
}

// ---------------- fused dual row-dot: s = sigmoid(X@sw+sb), dk = X@dw+db ----------------
__global__ __launch_bounds__(256) void rowdot2(const float* __restrict__ X, int K,
                                               const float* __restrict__ sw,
                                               const float* __restrict__ dw,
                                               const float* __restrict__ sb,
                                               const float* __restrict__ db,
                                               float* __restrict__ s_out,
                                               float* __restrict__ dk_out, int M) {
    int wave = (int)((blockIdx.x * (long long)blockDim.x + threadIdx.x) >> 6);
    int lane = threadIdx.x & 63;
    if (wave >= M) return;
    const float* xr = X + (long long)wave * K;
    float as = 0.f, ad = 0.f;
    for (int k = lane; k < K; k += 64) {
        float v = xr[k];
        as += v * sw[k];
        ad += v * dw[k];
    }
    #pragma unroll
    for (int off = 32; off; off >>= 1) {
        as += __shfl_down(as, off);
        ad += __shfl_down(ad, off);
    }
    if (lane == 0) {
        float sv = as + sb[0];
        s_out[wave] = 1.f / (1.f + __expf(-sv));
        dk_out[wave] = ad + db[0];
    }
}

// ---------------- CSR build: histogram, scan, scatter ----------------
__global__ __launch_bounds__(256) void hist2(const int* __restrict__ arow, int E,
                                             const int* __restrict__ krow, int EK,
                                             int* __restrict__ cnt, int N) {
    int i = blockIdx.x * blockDim.x + threadIdx.x;
    if (i < E)  atomicAdd(&cnt[arow[i]], 1);
    if (i < EK) atomicAdd(&cnt[N + krow[i]], 1);
}

// single-block exclusive scan of two N-length count arrays -> row_ptr[N+1]
__global__ __launch_bounds__(256) void scan_two(const int* __restrict__ cnt,
                                                int* __restrict__ rp_a,
                                                int* __restrict__ rp_k, int N) {
    __shared__ int psum[256];
    int t = threadIdx.x;
    for (int which = 0; which < 2; ++which) {
        const int* c = cnt + (size_t)which * N;
        int* rp = which ? rp_k : rp_a;
        int L = (N + 255) / 256;
        int beg = t * L;
        int end = min(beg + L, N);
        int s = 0;
        for (int i = beg; i < end; ++i) s += c[i];
        psum[t] = s;
        __syncthreads();
        for (int off = 1; off < 256; off <<= 1) {
            int tv = (t >= off) ? psum[t - off] : 0;
            __syncthreads();
            psum[t] += tv;
            __syncthreads();
        }
        int incl = psum[t];     // inclusive scan of per-thread sums
        int run = incl - s;     // exclusive start for this segment
        for (int i = beg; i < end; ++i) { rp[i] = run; run += c[i]; }
        if (t == 255) rp[N] = incl;
        __syncthreads();
    }
}

__global__ __launch_bounds__(256) void scatter2(const int* __restrict__ arow,
                                                const int* __restrict__ acol,
                                                const float* __restrict__ aval, int E,
                                                const int* __restrict__ krow,
                                                const int* __restrict__ kcol,
                                                const float* __restrict__ kval, int EK,
                                                const int* __restrict__ rp_a,
                                                const int* __restrict__ rp_k,
                                                int* __restrict__ cur, int N,
                                                int* __restrict__ scol_a, float* __restrict__ sval_a,
                                                int* __restrict__ scol_k, float* __restrict__ sval_k) {
    int i = blockIdx.x * blockDim.x + threadIdx.x;
    if (i < E) {
        int r = arow[i];
        int p = rp_a[r] + atomicAdd(&cur[r], 1);
        scol_a[p] = acol[i];
        sval_a[p] = aval[i];
    }
    if (i < EK) {
        int r = krow[i];
        int p = rp_k[r] + atomicAdd(&cur[N + r], 1);
        scol_k[p] = kcol[i];
        sval_k[p] = kval[i];
    }
}

// ---------------- fused CSR-SPMM(adj)+SPMM(knn)+combine, D=128 ----------------
// block = 256 threads = 2 rows x 128 cols
__global__ __launch_bounds__(256) void spmm_combine1(
    const int* __restrict__ rp_a, const int* __restrict__ scol_a, const float* __restrict__ sval_a,
    const int* __restrict__ rp_k, const int* __restrict__ scol_k, const float* __restrict__ sval_k,
    const float* __restrict__ sup, const float* __restrict__ s, const float* __restrict__ dk,
    const float* __restrict__ b, float* __restrict__ out, int Nrows) {
    int r = blockIdx.x * 2 + (threadIdx.x >> 7);
    int c = threadIdx.x & 127;
    if (r >= Nrows) return;

    float acc_a = 0.f, acc_k = 0.f;
    {
        int e = rp_a[r], e1 = rp_a[r + 1];
        for (; e + 2 <= e1; e += 2) {
            int c0 = scol_a[e], c1 = scol_a[e + 1];
            float v0 = sval_a[e], v1 = sval_a[e + 1];
            acc_a += v0 * sup[(size_t)c0 * 128 + c];
            acc_a += v1 * sup[(size_t)c1 * 128 + c];
        }
        if (e < e1) acc_a += sval_a[e] * sup[(size_t)scol_a[e] * 128 + c];
    }
    {
        int e = rp_k[r], e1 = rp_k[r + 1];
        for (; e + 2 <= e1; e += 2) {
            int c0 = scol_k[e], c1 = scol_k[e + 1];
            float v0 = sval_k[e], v1 = sval_k[e + 1];
            acc_k += v0 * sup[(size_t)c0 * 128 + c];
            acc_k += v1 * sup[(size_t)c1 * 128 + c];
        }
        if (e < e1) acc_k += sval_k[e] * sup[(size_t)scol_k[e] * 128 + c];
    }
    float si = s[r];
    float g = GAMMA * dk[r];
    size_t o = (size_t)r * 128 + c;
    out[o] = si * acc_a + (1.f - si) * acc_k + g * sup[o] + b[c] * (1.f + g);
}

// ---------------- fused CSR-SPMM x2 + combine + log_softmax, D=40 ----------------
// block = 256 threads = 4 waves, one row per wave (lanes 0..39 active for data)
__global__ __launch_bounds__(256) void spmm_combine2_lsm(
    const int* __restrict__ rp_a, const int* __restrict__ scol_a, const float* __restrict__ sval_a,
    const int* __restrict__ rp_k, const int* __restrict__ scol_k, const float* __restrict__ sval_k,
    const float* __restrict__ sup, const float* __restrict__ s, const float* __restrict__ dk,
    const float* __restrict__ b, float* __restrict__ out, int Nrows) {
    int r = blockIdx.x * 4 + (threadIdx.x >> 6);
    int lane = threadIdx.x & 63;
    if (r >= Nrows) return;
    int d = (lane < 40) ? lane : 0;

    float acc_a = 0.f, acc_k = 0.f;
    {
        int e = rp_a[r], e1 = rp_a[r + 1];
        for (; e + 2 <= e1; e += 2) {
            int c0 = scol_a[e], c1 = scol_a[e + 1];
            float v0 = sval_a[e], v1 = sval_a[e + 1];
            acc_a += v0 * sup[(size_t)c0 * 40 + d];
            acc_a += v1 * sup[(size_t)c1 * 40 + d];
        }
        if (e < e1) acc_a += sval_a[e] * sup[(size_t)scol_a[e] * 40 + d];
    }
    {
        int e = rp_k[r], e1 = rp_k[r + 1];
        for (; e + 2 <= e1; e += 2) {
            int c0 = scol_k[e], c1 = scol_k[e + 1];
            float v0 = sval_k[e], v1 = sval_k[e + 1];
            acc_k += v0 * sup[(size_t)c0 * 40 + d];
            acc_k += v1 * sup[(size_t)c1 * 40 + d];
        }
        if (e < e1) acc_k += sval_k[e] * sup[(size_t)scol_k[e] * 40 + d];
    }
    float si = s[r];
    float g = GAMMA * dk[r];
    float z = si * acc_a + (1.f - si) * acc_k + g * sup[(size_t)r * 40 + d] + b[d] * (1.f + g);
    if (lane >= 40) z = -INFINITY;
    float m = z;
    #pragma unroll
    for (int off = 32; off; off >>= 1) m = fmaxf(m, __shfl_xor(m, off));
    float ex = (lane < 40) ? __expf(z - m) : 0.f;
    float sum = ex;
    #pragma unroll
    for (int off = 32; off; off >>= 1) sum += __shfl_xor(sum, off);
    float lse = m + __logf(sum);
    if (lane < 40) out[(size_t)r * 40 + lane] = z - lse;
}

extern "C" void kernel_launch(void* const* d_in, const int* in_sizes, int n_in,
                              void* d_out, int out_size, void* d_ws, size_t ws_size,
                              hipStream_t stream) {
    const int N = 50000, F = 512, H = 128, C = 40;

    const float* fea     = (const float*)d_in[0];
    const int*   adj_row = (const int*)d_in[1];
    const int*   adj_col = (const int*)d_in[2];
    const float* adj_val = (const float*)d_in[3];
    const int*   knn_row = (const int*)d_in[4];
    const int*   knn_col = (const int*)d_in[5];
    const float* knn_val = (const float*)d_in[6];
    const float* W1      = (const float*)d_in[7];
    const float* b1      = (const float*)d_in[8];
    const float* W2      = (const float*)d_in[9];
    const float* b2      = (const float*)d_in[10];
    const float* score1  = (const float*)d_in[11];
    const float* score2  = (const float*)d_in[12];
    const float* sbias1  = (const float*)d_in[13];
    const float* sbias2  = (const float*)d_in[14];
    const float* Dk1     = (const float*)d_in[15];
    const float* Dk2     = (const float*)d_in[16];
    const float* Dbias1  = (const float*)d_in[17];
    const float* Dbias2  = (const float*)d_in[18];

    const int E  = in_sizes[1];
    const int EK = in_sizes[4];

    // output layout: [log_softmax (N*C)] [embedding (N*H)]
    float* out_lsm = (float*)d_out;
    float* emb     = out_lsm + (size_t)N * C;

    // workspace carve (≈49 MB)
    char* w = (char*)d_ws;
    float* sup1   = (float*)w; w += (size_t)N * 128 * 4;
    float* sup2   = (float*)w; w += (size_t)N * 40 * 4;
    float* s_buf  = (float*)w; w += (size_t)N * 4;
    float* dk_buf = (float*)w; w += (size_t)N * 4;
    int* rp_a     = (int*)w;   w += (size_t)(N + 1) * 4;
    int* rp_k     = (int*)w;   w += (size_t)(N + 1) * 4;
    int* cnt      = (int*)w;   w += (size_t)2 * N * 4;
    int* scol_a   = (int*)w;   w += (size_t)E * 4;
    float* sval_a = (float*)w; w += (size_t)E * 4;
    int* scol_k   = (int*)w;   w += (size_t)EK * 4;
    float* sval_k = (float*)w; w += (size_t)EK * 4;

    int egrid = (max(E, EK) + 255) / 256;

    // ---- CSR build (graph is same for both layers) ----
    hipMemsetAsync(cnt, 0, (size_t)2 * N * 4, stream);
    hist2<<<egrid, 256, 0, stream>>>(adj_row, E, knn_row, EK, cnt, N);
    scan_two<<<1, 256, 0, stream>>>(cnt, rp_a, rp_k, N);
    hipMemsetAsync(cnt, 0, (size_t)2 * N * 4, stream);
    scatter2<<<egrid, 256, 0, stream>>>(adj_row, adj_col, adj_val, E,
                                        knn_row, knn_col, knn_val, EK,
                                        rp_a, rp_k, cnt, N,
                                        scol_a, sval_a, scol_k, sval_k);

    // ---------- layer 1 ----------
    {
        dim3 grid((N + BM - 1) / BM, (H + BN - 1) / BN);
        gemm_f32<<<grid, 256, 0, stream>>>(fea, W1, sup1, N, H, F);
    }
    rowdot2<<<(N + 3) / 4, 256, 0, stream>>>(fea, F, score1, Dk1, sbias1, Dbias1,
                                             s_buf, dk_buf, N);
    spmm_combine1<<<(N + 1) / 2, 256, 0, stream>>>(rp_a, scol_a, sval_a,
                                                   rp_k, scol_k, sval_k,
                                                   sup1, s_buf, dk_buf, b1, emb, N);

    // ---------- layer 2 ----------
    {
        dim3 grid((N + BM - 1) / BM, (C + BN - 1) / BN);
        gemm_f32<<<grid, 256, 0, stream>>>(emb, W2, sup2, N, C, H);
    }
    rowdot2<<<(N + 3) / 4, 256, 0, stream>>>(emb, H, score2, Dk2, sbias2, Dbias2,
                                             s_buf, dk_buf, N);
    spmm_combine2_lsm<<<(N + 3) / 4, 256, 0, stream>>>(rp_a, scol_a, sval_a,
                                                       rp_k, scol_k, sval_k,
                                                       sup2, s_buf, dk_buf, b2, out_lsm, N);

    (void)n_in; (void)out_size; (void)ws_size;
}

// Round 4
// 805.012 us; speedup vs baseline: 1.8573x; 1.2989x over previous
//
#include <hip/hip_runtime.h>
#include <hip/hip_bf16.h>
#include <cstdint>

#define GAMMA 0.1f

typedef unsigned int  uint32;
typedef unsigned short ushort16;
typedef float f32x4 __attribute__((ext_vector_type(4)));
typedef __bf16 bf16x8 __attribute__((ext_vector_type(8)));

union U16x8 { uint4 u4; bf16x8 bv; };

static __device__ __forceinline__ ushort16 f2bf(float f) {
    union { float f; uint32 u; } x; x.f = f;
    uint32 r = (x.u + 0x7FFFu + ((x.u >> 16) & 1u)) >> 16;
    return (ushort16)r;
}
static __device__ __forceinline__ uint32 pack2bf(float lo, float hi) {
    return (uint32)f2bf(lo) | ((uint32)f2bf(hi) << 16);
}
static __device__ __forceinline__ float bflo(uint32 u) { return __uint_as_float(u << 16); }
static __device__ __forceinline__ float bfhi(uint32 u) { return __uint_as_float(u & 0xFFFF0000u); }

// ---------- prep: W1^T, W2^T (bf16, W2 padded to 48 cols) ----------
__global__ __launch_bounds__(256) void prep_wt(const float* __restrict__ W1,
                                               const float* __restrict__ W2,
                                               ushort16* __restrict__ W1bt,
                                               ushort16* __restrict__ W2bt) {
    int t = blockIdx.x * 256 + threadIdx.x;
    if (t < 128 * 512) { int c = t >> 9, k = t & 511; W1bt[t] = f2bf(W1[k * 128 + c]); }
    if (t < 48 * 128)  { int c = t >> 7, k = t & 127; W2bt[t] = f2bf(c < 40 ? W2[k * 40 + c] : 0.f); }
}

// ---------- CSR build ----------
__global__ __launch_bounds__(256) void hist2(const int* __restrict__ arow, int E,
                                             const int* __restrict__ krow, int EK,
                                             int* __restrict__ cnt, int N) {
    int i = blockIdx.x * blockDim.x + threadIdx.x;
    if (i < E)  atomicAdd(&cnt[arow[i]], 1);
    if (i < EK) atomicAdd(&cnt[N + krow[i]], 1);
}

__global__ __launch_bounds__(1024) void scan_two(const int* __restrict__ cnt,
                                                 int* __restrict__ rp_a,
                                                 int* __restrict__ rp_k, int N) {
    __shared__ int psum[1024];
    int t = threadIdx.x;
    for (int which = 0; which < 2; ++which) {
        const int* c = cnt + (size_t)which * N;
        int* rp = which ? rp_k : rp_a;
        int L = (N + 1023) / 1024;
        int beg = min(t * L, N);
        int end = min(beg + L, N);
        int sm = 0;
        for (int i = beg; i < end; ++i) sm += c[i];
        psum[t] = sm;
        __syncthreads();
        for (int off = 1; off < 1024; off <<= 1) {
            int tv = (t >= off) ? psum[t - off] : 0;
            __syncthreads();
            psum[t] += tv;
            __syncthreads();
        }
        int incl = psum[t];
        int run = incl - sm;
        for (int i = beg; i < end; ++i) { rp[i] = run; run += c[i]; }
        if (t == 1023) rp[N] = incl;
        __syncthreads();
    }
}

__global__ __launch_bounds__(256) void scatter2(const int* __restrict__ arow,
                                                const int* __restrict__ acol,
                                                const float* __restrict__ aval, int E,
                                                const int* __restrict__ krow,
                                                const int* __restrict__ kcol,
                                                const float* __restrict__ kval, int EK,
                                                const int* __restrict__ rp_a,
                                                const int* __restrict__ rp_k,
                                                int* __restrict__ cur, int N,
                                                int* __restrict__ scol_a, float* __restrict__ sval_a,
                                                int* __restrict__ scol_k, float* __restrict__ sval_k) {
    int i = blockIdx.x * blockDim.x + threadIdx.x;
    if (i < E) {
        int r = arow[i];
        int p = rp_a[r] + atomicAdd(&cur[r], 1);
        scol_a[p] = acol[i];
        sval_a[p] = aval[i];
    }
    if (i < EK) {
        int r = krow[i];
        int p = rp_k[r] + atomicAdd(&cur[N + r], 1);
        scol_k[p] = kcol[i];
        sval_k[p] = kval[i];
    }
}

// ---------- GEMM1: sup1b[M,128](bf16) = fea[M,512](f32->bf16) @ W1; fused s/Dk gates ----------
__global__ __launch_bounds__(256) void gemm1_mfma(const float* __restrict__ A,
                                                  const ushort16* __restrict__ Bt, // [128][512]
                                                  const float* __restrict__ s1w,
                                                  const float* __restrict__ d1w,
                                                  const float* __restrict__ s1b,
                                                  const float* __restrict__ d1b,
                                                  ushort16* __restrict__ Cb, // [M][128]
                                                  float* __restrict__ s_out,
                                                  float* __restrict__ dk_out, int M) {
    int w = threadIdx.x >> 6, lane = threadIdx.x & 63;
    int row16 = lane & 15, kc = lane >> 4;
    int wrow0 = blockIdx.x * 64 + w * 16;
    int r = wrow0 + row16;
    int rc = min(r, M - 1);
    const float* arow = A + (size_t)rc * 512;

    f32x4 acc[8];
    #pragma unroll
    for (int c = 0; c < 8; ++c) acc[c] = (f32x4){0.f, 0.f, 0.f, 0.f};
    float sdot = 0.f, ddot = 0.f;

    for (int ks = 0; ks < 16; ++ks) {
        int kb = ks * 32 + kc * 8;
        float4 a0 = *reinterpret_cast<const float4*>(arow + kb);
        float4 a1 = *reinterpret_cast<const float4*>(arow + kb + 4);
        float4 sw0 = *reinterpret_cast<const float4*>(s1w + kb);
        float4 sw1 = *reinterpret_cast<const float4*>(s1w + kb + 4);
        float4 dw0 = *reinterpret_cast<const float4*>(d1w + kb);
        float4 dw1 = *reinterpret_cast<const float4*>(d1w + kb + 4);
        sdot += a0.x * sw0.x + a0.y * sw0.y + a0.z * sw0.z + a0.w * sw0.w +
                a1.x * sw1.x + a1.y * sw1.y + a1.z * sw1.z + a1.w * sw1.w;
        ddot += a0.x * dw0.x + a0.y * dw0.y + a0.z * dw0.z + a0.w * dw0.w +
                a1.x * dw1.x + a1.y * dw1.y + a1.z * dw1.z + a1.w * dw1.w;
        U16x8 ua;
        ua.u4 = make_uint4(pack2bf(a0.x, a0.y), pack2bf(a0.z, a0.w),
                           pack2bf(a1.x, a1.y), pack2bf(a1.z, a1.w));
        #pragma unroll
        for (int c = 0; c < 8; ++c) {
            U16x8 ub;
            ub.u4 = *reinterpret_cast<const uint4*>(Bt + (size_t)(c * 16 + row16) * 512 + kb);
            acc[c] = __builtin_amdgcn_mfma_f32_16x16x32_bf16(ua.bv, ub.bv, acc[c], 0, 0, 0);
        }
    }

    // reduce gates across the 4 kc-lanes holding the same row
    sdot += __shfl_xor(sdot, 16); sdot += __shfl_xor(sdot, 32);
    ddot += __shfl_xor(ddot, 16); ddot += __shfl_xor(ddot, 32);
    if (kc == 0 && r < M) {
        s_out[r] = 1.f / (1.f + __expf(-(sdot + s1b[0])));
        dk_out[r] = ddot + d1b[0];
    }

    #pragma unroll
    for (int c = 0; c < 8; ++c) {
        #pragma unroll
        for (int i = 0; i < 4; ++i) {
            int orow = wrow0 + (lane >> 4) * 4 + i;
            if (orow < M) Cb[(size_t)orow * 128 + c * 16 + row16] = f2bf(acc[c][i]);
        }
    }
}

// ---------- GEMM2: sup2[M,40](f32)+sup2b(bf16) = embb[M,128](bf16) @ W2 ----------
__global__ __launch_bounds__(256) void gemm2_mfma(const ushort16* __restrict__ Ab, // [M][128]
                                                  const ushort16* __restrict__ Bt, // [48][128]
                                                  float* __restrict__ C,           // [M][40]
                                                  ushort16* __restrict__ Cb,       // [M][40]
                                                  int M) {
    int w = threadIdx.x >> 6, lane = threadIdx.x & 63;
    int row16 = lane & 15, kc = lane >> 4;
    int wrow0 = blockIdx.x * 64 + w * 16;
    int r = wrow0 + row16;
    int rc = min(r, M - 1);

    f32x4 acc[3];
    #pragma unroll
    for (int c = 0; c < 3; ++c) acc[c] = (f32x4){0.f, 0.f, 0.f, 0.f};

    #pragma unroll
    for (int ks = 0; ks < 4; ++ks) {
        int kb = ks * 32 + kc * 8;
        U16x8 ua;
        ua.u4 = *reinterpret_cast<const uint4*>(Ab + (size_t)rc * 128 + kb);
        #pragma unroll
        for (int c = 0; c < 3; ++c) {
            U16x8 ub;
            ub.u4 = *reinterpret_cast<const uint4*>(Bt + (size_t)(c * 16 + row16) * 128 + kb);
            acc[c] = __builtin_amdgcn_mfma_f32_16x16x32_bf16(ua.bv, ub.bv, acc[c], 0, 0, 0);
        }
    }

    #pragma unroll
    for (int c = 0; c < 3; ++c) {
        int col = c * 16 + row16;
        #pragma unroll
        for (int i = 0; i < 4; ++i) {
            int orow = wrow0 + (lane >> 4) * 4 + i;
            if (orow < M && col < 40) {
                C[(size_t)orow * 40 + col] = acc[c][i];
                Cb[(size_t)orow * 40 + col] = f2bf(acc[c][i]);
            }
        }
    }
}

// ---------- fused SPMM(adj)+SPMM(knn)+combine layer1 + layer2 gates ----------
// one wave per row; lane holds cols (2*lane, 2*lane+1)
__global__ __launch_bounds__(256) void spmm_combine1(
    const int* __restrict__ rp_a, const int* __restrict__ scol_a, const float* __restrict__ sval_a,
    const int* __restrict__ rp_k, const int* __restrict__ scol_k, const float* __restrict__ sval_k,
    const ushort16* __restrict__ supb, const float* __restrict__ s, const float* __restrict__ dk,
    const float* __restrict__ b1,
    const float* __restrict__ s2w, const float* __restrict__ d2w,
    const float* __restrict__ s2b, const float* __restrict__ d2b,
    float* __restrict__ emb, ushort16* __restrict__ embb,
    float* __restrict__ s_out, float* __restrict__ dk_out, int N) {
    int w = threadIdx.x >> 6, lane = threadIdx.x & 63;
    int r = blockIdx.x * 4 + w;
    if (r >= N) return;
    const uint32* su = (const uint32*)supb;

    float a0 = 0.f, a1 = 0.f, k0 = 0.f, k1 = 0.f;
    {
        int e = rp_a[r], e1 = rp_a[r + 1];
        for (; e + 2 <= e1; e += 2) {
            int c0 = scol_a[e], c1 = scol_a[e + 1];
            float v0 = sval_a[e], v1 = sval_a[e + 1];
            uint32 u0 = su[(size_t)c0 * 64 + lane];
            uint32 u1 = su[(size_t)c1 * 64 + lane];
            a0 += v0 * bflo(u0) + v1 * bflo(u1);
            a1 += v0 * bfhi(u0) + v1 * bfhi(u1);
        }
        if (e < e1) {
            uint32 u0 = su[(size_t)scol_a[e] * 64 + lane];
            float v0 = sval_a[e];
            a0 += v0 * bflo(u0); a1 += v0 * bfhi(u0);
        }
    }
    {
        int e = rp_k[r], e1 = rp_k[r + 1];
        for (; e + 2 <= e1; e += 2) {
            int c0 = scol_k[e], c1 = scol_k[e + 1];
            float v0 = sval_k[e], v1 = sval_k[e + 1];
            uint32 u0 = su[(size_t)c0 * 64 + lane];
            uint32 u1 = su[(size_t)c1 * 64 + lane];
            k0 += v0 * bflo(u0) + v1 * bflo(u1);
            k1 += v0 * bfhi(u0) + v1 * bfhi(u1);
        }
        if (e < e1) {
            uint32 u0 = su[(size_t)scol_k[e] * 64 + lane];
            float v0 = sval_k[e];
            k0 += v0 * bflo(u0); k1 += v0 * bfhi(u0);
        }
    }

    float si = s[r];
    float g = GAMMA * dk[r];
    uint32 ui = su[(size_t)r * 64 + lane];
    int c0i = lane * 2, c1i = lane * 2 + 1;
    float o0 = si * a0 + (1.f - si) * k0 + g * bflo(ui) + b1[c0i] * (1.f + g);
    float o1 = si * a1 + (1.f - si) * k1 + g * bfhi(ui) + b1[c1i] * (1.f + g);

    *reinterpret_cast<float2*>(emb + (size_t)r * 128 + c0i) = make_float2(o0, o1);
    ((uint32*)embb)[(size_t)r * 64 + lane] = pack2bf(o0, o1);

    // layer-2 gates from the fp32 row
    float as = o0 * s2w[c0i] + o1 * s2w[c1i];
    float ad = o0 * d2w[c0i] + o1 * d2w[c1i];
    #pragma unroll
    for (int off = 32; off; off >>= 1) {
        as += __shfl_xor(as, off);
        ad += __shfl_xor(ad, off);
    }
    if (lane == 0) {
        s_out[r] = 1.f / (1.f + __expf(-(as + s2b[0])));
        dk_out[r] = ad + d2b[0];
    }
}

// ---------- fused SPMM x2 + combine + log_softmax layer2 ----------
// one wave per row; two 20-lane groups process alternate edges; cols packed 2/lane
__global__ __launch_bounds__(256) void spmm_combine2_lsm(
    const int* __restrict__ rp_a, const int* __restrict__ scol_a, const float* __restrict__ sval_a,
    const int* __restrict__ rp_k, const int* __restrict__ scol_k, const float* __restrict__ sval_k,
    const ushort16* __restrict__ supb, const float* __restrict__ supf,
    const float* __restrict__ s, const float* __restrict__ dk,
    const float* __restrict__ b2, float* __restrict__ out, int N) {
    int w = threadIdx.x >> 6, lane = threadIdx.x & 63;
    int r = blockIdx.x * 4 + w;
    if (r >= N) return;
    int g = lane >> 5, li = lane & 31;
    bool act = li < 20;
    const uint32* su = (const uint32*)supb;

    float a0 = 0.f, a1 = 0.f, k0 = 0.f, k1 = 0.f;
    {
        int e1 = rp_a[r + 1];
        for (int e = rp_a[r] + g; e < e1; e += 2) {
            int c = scol_a[e];
            float v = sval_a[e];
            if (act) {
                uint32 u = su[(size_t)c * 20 + li];
                a0 += v * bflo(u); a1 += v * bfhi(u);
            }
        }
    }
    {
        int e1 = rp_k[r + 1];
        for (int e = rp_k[r] + g; e < e1; e += 2) {
            int c = scol_k[e];
            float v = sval_k[e];
            if (act) {
                uint32 u = su[(size_t)c * 20 + li];
                k0 += v * bflo(u); k1 += v * bfhi(u);
            }
        }
    }
    a0 += __shfl_xor(a0, 32); a1 += __shfl_xor(a1, 32);
    k0 += __shfl_xor(k0, 32); k1 += __shfl_xor(k1, 32);

    float si = s[r];
    float gg = GAMMA * dk[r];
    float z0 = -INFINITY, z1 = -INFINITY;
    bool lead = act && (lane < 32);
    if (lead) {
        float2 iv = *reinterpret_cast<const float2*>(supf + (size_t)r * 40 + li * 2);
        z0 = si * a0 + (1.f - si) * k0 + gg * iv.x + b2[li * 2] * (1.f + gg);
        z1 = si * a1 + (1.f - si) * k1 + gg * iv.y + b2[li * 2 + 1] * (1.f + gg);
    }
    float m = fmaxf(z0, z1);
    #pragma unroll
    for (int off = 16; off; off >>= 1) m = fmaxf(m, __shfl_xor(m, off));
    float ex = lead ? (__expf(z0 - m) + __expf(z1 - m)) : 0.f;
    #pragma unroll
    for (int off = 16; off; off >>= 1) ex += __shfl_xor(ex, off);
    float lse = m + __logf(ex);
    if (lead)
        *reinterpret_cast<float2*>(out + (size_t)r * 40 + li * 2) = make_float2(z0 - lse, z1 - lse);
}

static inline size_t align256(size_t x) { return (x + 255) & ~(size_t)255; }

extern "C" void kernel_launch(void* const* d_in, const int* in_sizes, int n_in,
                              void* d_out, int out_size, void* d_ws, size_t ws_size,
                              hipStream_t stream) {
    const int N = 50000, C = 40;

    const float* fea     = (const float*)d_in[0];
    const int*   adj_row = (const int*)d_in[1];
    const int*   adj_col = (const int*)d_in[2];
    const float* adj_val = (const float*)d_in[3];
    const int*   knn_row = (const int*)d_in[4];
    const int*   knn_col = (const int*)d_in[5];
    const float* knn_val = (const float*)d_in[6];
    const float* W1      = (const float*)d_in[7];
    const float* b1      = (const float*)d_in[8];
    const float* W2      = (const float*)d_in[9];
    const float* b2      = (const float*)d_in[10];
    const float* score1  = (const float*)d_in[11];
    const float* score2  = (const float*)d_in[12];
    const float* sbias1  = (const float*)d_in[13];
    const float* sbias2  = (const float*)d_in[14];
    const float* Dk1     = (const float*)d_in[15];
    const float* Dk2     = (const float*)d_in[16];
    const float* Dbias1  = (const float*)d_in[17];
    const float* Dbias2  = (const float*)d_in[18];

    const int E  = in_sizes[1];
    const int EK = in_sizes[4];

    float* out_lsm = (float*)d_out;
    float* emb     = out_lsm + (size_t)N * C;   // fp32 embedding output (x1)

    // workspace carve
    char* wp = (char*)d_ws;
    ushort16* W1bt = (ushort16*)wp; wp += align256((size_t)128 * 512 * 2);
    ushort16* W2bt = (ushort16*)wp; wp += align256((size_t)48 * 128 * 2);
    ushort16* sup1b = (ushort16*)wp; wp += align256((size_t)N * 128 * 2);
    ushort16* embb  = (ushort16*)wp; wp += align256((size_t)N * 128 * 2);
    float* sup2     = (float*)wp;   wp += align256((size_t)N * 40 * 4);
    ushort16* sup2b = (ushort16*)wp; wp += align256((size_t)N * 40 * 2);
    float* s_buf  = (float*)wp; wp += align256((size_t)N * 4);
    float* dk_buf = (float*)wp; wp += align256((size_t)N * 4);
    int* rp_a = (int*)wp; wp += align256((size_t)(N + 1) * 4);
    int* rp_k = (int*)wp; wp += align256((size_t)(N + 1) * 4);
    int* cnt  = (int*)wp; wp += align256((size_t)2 * N * 4);
    int* scol_a   = (int*)wp;   wp += align256((size_t)E * 4);
    float* sval_a = (float*)wp; wp += align256((size_t)E * 4);
    int* scol_k   = (int*)wp;   wp += align256((size_t)EK * 4);
    float* sval_k = (float*)wp; wp += align256((size_t)EK * 4);

    int egrid = (max(E, EK) + 255) / 256;
    int mgrid = (N + 63) / 64;

    // prep + CSR build
    prep_wt<<<256, 256, 0, stream>>>(W1, W2, W1bt, W2bt);
    hipMemsetAsync(cnt, 0, (size_t)2 * N * 4, stream);
    hist2<<<egrid, 256, 0, stream>>>(adj_row, E, knn_row, EK, cnt, N);
    scan_two<<<1, 1024, 0, stream>>>(cnt, rp_a, rp_k, N);
    hipMemsetAsync(cnt, 0, (size_t)2 * N * 4, stream);
    scatter2<<<egrid, 256, 0, stream>>>(adj_row, adj_col, adj_val, E,
                                        knn_row, knn_col, knn_val, EK,
                                        rp_a, rp_k, cnt, N,
                                        scol_a, sval_a, scol_k, sval_k);

    // layer 1
    gemm1_mfma<<<mgrid, 256, 0, stream>>>(fea, W1bt, score1, Dk1, sbias1, Dbias1,
                                          sup1b, s_buf, dk_buf, N);
    spmm_combine1<<<(N + 3) / 4, 256, 0, stream>>>(rp_a, scol_a, sval_a,
                                                   rp_k, scol_k, sval_k,
                                                   sup1b, s_buf, dk_buf, b1,
                                                   score2, Dk2, sbias2, Dbias2,
                                                   emb, embb, s_buf, dk_buf, N);

    // layer 2
    gemm2_mfma<<<mgrid, 256, 0, stream>>>(embb, W2bt, sup2, sup2b, N);
    spmm_combine2_lsm<<<(N + 3) / 4, 256, 0, stream>>>(rp_a, scol_a, sval_a,
                                                       rp_k, scol_k, sval_k,
                                                       sup2b, sup2, s_buf, dk_buf,
                                                       b2, out_lsm, N);

    (void)n_in; (void)out_size; (void)ws_size;
}

// Round 5
// 673.419 us; speedup vs baseline: 2.2202x; 1.1954x over previous
//
#include <hip/hip_runtime.h>
#include <hip/hip_bf16.h>
#include <cstdint>

#define GAMMA 0.1f

typedef unsigned int  uint32;
typedef unsigned short ushort16;
typedef float f32x4 __attribute__((ext_vector_type(4)));
typedef __bf16 bf16x8 __attribute__((ext_vector_type(8)));

union U16x8 { uint4 u4; bf16x8 bv; };

static __device__ __forceinline__ ushort16 f2bf(float f) {
    union { float f; uint32 u; } x; x.f = f;
    uint32 r = (x.u + 0x7FFFu + ((x.u >> 16) & 1u)) >> 16;
    return (ushort16)r;
}
static __device__ __forceinline__ uint32 pack2bf(float lo, float hi) {
    return (uint32)f2bf(lo) | ((uint32)f2bf(hi) << 16);
}
static __device__ __forceinline__ float bflo(uint32 u) { return __uint_as_float(u << 16); }
static __device__ __forceinline__ float bfhi(uint32 u) { return __uint_as_float(u & 0xFFFF0000u); }

// ---------- prep: W1^T, W2^T (bf16, W2 padded to 48 cols) ----------
__global__ __launch_bounds__(256) void prep_wt(const float* __restrict__ W1,
                                               const float* __restrict__ W2,
                                               ushort16* __restrict__ W1bt,
                                               ushort16* __restrict__ W2bt) {
    int t = blockIdx.x * 256 + threadIdx.x;
    if (t < 128 * 512) { int c = t >> 9, k = t & 511; W1bt[t] = f2bf(W1[k * 128 + c]); }
    if (t < 48 * 128)  { int c = t >> 7, k = t & 127; W2bt[t] = f2bf(c < 40 ? W2[k * 40 + c] : 0.f); }
}

// ---------- CSR build ----------
__global__ __launch_bounds__(256) void hist2(const int* __restrict__ arow, int E,
                                             const int* __restrict__ krow, int EK,
                                             int* __restrict__ cnt, int N) {
    int i = blockIdx.x * blockDim.x + threadIdx.x;
    if (i < E)  atomicAdd(&cnt[arow[i]], 1);
    if (i < EK) atomicAdd(&cnt[N + krow[i]], 1);
}

// 3-phase hierarchical scan over cnt[0..N) and cnt[N..2N)
#define SEG 4096

__global__ __launch_bounds__(256) void scan_partial(const int* __restrict__ cnt,
                                                    int* __restrict__ partial, int N, int NB) {
    int which = blockIdx.x / NB, seg = blockIdx.x % NB;
    const int* c = cnt + (size_t)which * N;
    int base = seg * SEG;
    int s = 0;
    for (int i = threadIdx.x; i < SEG; i += 256) {
        int idx = base + i;
        if (idx < N) s += c[idx];
    }
    #pragma unroll
    for (int off = 32; off; off >>= 1) s += __shfl_down(s, off);
    __shared__ int sm[4];
    if ((threadIdx.x & 63) == 0) sm[threadIdx.x >> 6] = s;
    __syncthreads();
    if (threadIdx.x == 0) partial[blockIdx.x] = sm[0] + sm[1] + sm[2] + sm[3];
}

__global__ void scan_offsets(int* __restrict__ partial, int NB,
                             int* __restrict__ rp_a, int* __restrict__ rp_k, int N) {
    if (threadIdx.x == 0) {
        int run = 0;
        for (int i = 0; i < NB; ++i) { int v = partial[i]; partial[i] = run; run += v; }
        rp_a[N] = run;
        run = 0;
        for (int i = NB; i < 2 * NB; ++i) { int v = partial[i]; partial[i] = run; run += v; }
        rp_k[N] = run;
    }
}

// writes rp and (in place over cnt) the scatter cursors initialized to rp
__global__ __launch_bounds__(256) void scan_final(int* __restrict__ cnt,
                                                  const int* __restrict__ partial,
                                                  int* __restrict__ rp_a, int* __restrict__ rp_k,
                                                  int N, int NB) {
    int which = blockIdx.x / NB, seg = blockIdx.x % NB;
    int* c = cnt + (size_t)which * N;
    int* rp = which ? rp_k : rp_a;
    int base = seg * SEG;
    int tbeg = base + threadIdx.x * 16;
    int loc[16];
    int s = 0;
    #pragma unroll
    for (int j = 0; j < 16; ++j) {
        int idx = tbeg + j;
        loc[j] = (idx < N) ? c[idx] : 0;
        s += loc[j];
    }
    __shared__ int ps[256];
    ps[threadIdx.x] = s;
    __syncthreads();
    for (int off = 1; off < 256; off <<= 1) {
        int v = (threadIdx.x >= off) ? ps[threadIdx.x - off] : 0;
        __syncthreads();
        ps[threadIdx.x] += v;
        __syncthreads();
    }
    int run = partial[blockIdx.x] + ps[threadIdx.x] - s;
    #pragma unroll
    for (int j = 0; j < 16; ++j) {
        int idx = tbeg + j;
        if (idx < N) { rp[idx] = run; c[idx] = run; run += loc[j]; }
    }
}

__global__ __launch_bounds__(256) void scatter2(const int* __restrict__ arow,
                                                const int* __restrict__ acol,
                                                const float* __restrict__ aval, int E,
                                                const int* __restrict__ krow,
                                                const int* __restrict__ kcol,
                                                const float* __restrict__ kval, int EK,
                                                int* __restrict__ cur, int N,
                                                int* __restrict__ scol_a, float* __restrict__ sval_a,
                                                int* __restrict__ scol_k, float* __restrict__ sval_k) {
    int i = blockIdx.x * blockDim.x + threadIdx.x;
    if (i < E) {
        int p = atomicAdd(&cur[arow[i]], 1);
        scol_a[p] = acol[i];
        sval_a[p] = aval[i];
    }
    if (i < EK) {
        int p = atomicAdd(&cur[N + krow[i]], 1);
        scol_k[p] = kcol[i];
        sval_k[p] = kval[i];
    }
}

// ---------- GEMM1: sup1b[M,128](bf16) = fea[M,512](f32->bf16) @ W1; fused s/Dk gates ----------
__global__ __launch_bounds__(256) void gemm1_mfma(const float* __restrict__ A,
                                                  const ushort16* __restrict__ Bt, // [128][512]
                                                  const float* __restrict__ s1w,
                                                  const float* __restrict__ d1w,
                                                  const float* __restrict__ s1b,
                                                  const float* __restrict__ d1b,
                                                  ushort16* __restrict__ Cb, // [M][128]
                                                  float* __restrict__ s_out,
                                                  float* __restrict__ dk_out, int M) {
    int w = threadIdx.x >> 6, lane = threadIdx.x & 63;
    int row16 = lane & 15, kc = lane >> 4;
    int wrow0 = blockIdx.x * 64 + w * 16;
    int r = wrow0 + row16;
    int rc = min(r, M - 1);
    const float* arow = A + (size_t)rc * 512;

    f32x4 acc[8];
    #pragma unroll
    for (int c = 0; c < 8; ++c) acc[c] = (f32x4){0.f, 0.f, 0.f, 0.f};
    float sdot = 0.f, ddot = 0.f;

    for (int ks = 0; ks < 16; ++ks) {
        int kb = ks * 32 + kc * 8;
        float4 a0 = *reinterpret_cast<const float4*>(arow + kb);
        float4 a1 = *reinterpret_cast<const float4*>(arow + kb + 4);
        float4 sw0 = *reinterpret_cast<const float4*>(s1w + kb);
        float4 sw1 = *reinterpret_cast<const float4*>(s1w + kb + 4);
        float4 dw0 = *reinterpret_cast<const float4*>(d1w + kb);
        float4 dw1 = *reinterpret_cast<const float4*>(d1w + kb + 4);
        sdot += a0.x * sw0.x + a0.y * sw0.y + a0.z * sw0.z + a0.w * sw0.w +
                a1.x * sw1.x + a1.y * sw1.y + a1.z * sw1.z + a1.w * sw1.w;
        ddot += a0.x * dw0.x + a0.y * dw0.y + a0.z * dw0.z + a0.w * dw0.w +
                a1.x * dw1.x + a1.y * dw1.y + a1.z * dw1.z + a1.w * dw1.w;
        U16x8 ua;
        ua.u4 = make_uint4(pack2bf(a0.x, a0.y), pack2bf(a0.z, a0.w),
                           pack2bf(a1.x, a1.y), pack2bf(a1.z, a1.w));
        #pragma unroll
        for (int c = 0; c < 8; ++c) {
            U16x8 ub;
            ub.u4 = *reinterpret_cast<const uint4*>(Bt + (size_t)(c * 16 + row16) * 512 + kb);
            acc[c] = __builtin_amdgcn_mfma_f32_16x16x32_bf16(ua.bv, ub.bv, acc[c], 0, 0, 0);
        }
    }

    sdot += __shfl_xor(sdot, 16); sdot += __shfl_xor(sdot, 32);
    ddot += __shfl_xor(ddot, 16); ddot += __shfl_xor(ddot, 32);
    if (kc == 0 && r < M) {
        s_out[r] = 1.f / (1.f + __expf(-(sdot + s1b[0])));
        dk_out[r] = ddot + d1b[0];
    }

    #pragma unroll
    for (int c = 0; c < 8; ++c) {
        #pragma unroll
        for (int i = 0; i < 4; ++i) {
            int orow = wrow0 + (lane >> 4) * 4 + i;
            if (orow < M) Cb[(size_t)orow * 128 + c * 16 + row16] = f2bf(acc[c][i]);
        }
    }
}

// ---------- GEMM2: sup2[M,40](f32)+sup2b(bf16) = embb[M,128](bf16) @ W2 ----------
__global__ __launch_bounds__(256) void gemm2_mfma(const ushort16* __restrict__ Ab, // [M][128]
                                                  const ushort16* __restrict__ Bt, // [48][128]
                                                  float* __restrict__ C,           // [M][40]
                                                  ushort16* __restrict__ Cb,       // [M][40]
                                                  int M) {
    int w = threadIdx.x >> 6, lane = threadIdx.x & 63;
    int row16 = lane & 15, kc = lane >> 4;
    int wrow0 = blockIdx.x * 64 + w * 16;
    int r = wrow0 + row16;
    int rc = min(r, M - 1);

    f32x4 acc[3];
    #pragma unroll
    for (int c = 0; c < 3; ++c) acc[c] = (f32x4){0.f, 0.f, 0.f, 0.f};

    #pragma unroll
    for (int ks = 0; ks < 4; ++ks) {
        int kb = ks * 32 + kc * 8;
        U16x8 ua;
        ua.u4 = *reinterpret_cast<const uint4*>(Ab + (size_t)rc * 128 + kb);
        #pragma unroll
        for (int c = 0; c < 3; ++c) {
            U16x8 ub;
            ub.u4 = *reinterpret_cast<const uint4*>(Bt + (size_t)(c * 16 + row16) * 128 + kb);
            acc[c] = __builtin_amdgcn_mfma_f32_16x16x32_bf16(ua.bv, ub.bv, acc[c], 0, 0, 0);
        }
    }

    #pragma unroll
    for (int c = 0; c < 3; ++c) {
        int col = c * 16 + row16;
        #pragma unroll
        for (int i = 0; i < 4; ++i) {
            int orow = wrow0 + (lane >> 4) * 4 + i;
            if (orow < M && col < 40) {
                C[(size_t)orow * 40 + col] = acc[c][i];
                Cb[(size_t)orow * 40 + col] = f2bf(acc[c][i]);
            }
        }
    }
}

// ---------- fused SPMM(adj)+SPMM(knn)+combine layer1 + layer2 gates ----------
__global__ __launch_bounds__(256) void spmm_combine1(
    const int* __restrict__ rp_a, const int* __restrict__ scol_a, const float* __restrict__ sval_a,
    const int* __restrict__ rp_k, const int* __restrict__ scol_k, const float* __restrict__ sval_k,
    const ushort16* __restrict__ supb, const float* __restrict__ s, const float* __restrict__ dk,
    const float* __restrict__ b1,
    const float* __restrict__ s2w, const float* __restrict__ d2w,
    const float* __restrict__ s2b, const float* __restrict__ d2b,
    float* __restrict__ emb, ushort16* __restrict__ embb,
    float* __restrict__ s_out, float* __restrict__ dk_out, int N) {
    int w = threadIdx.x >> 6, lane = threadIdx.x & 63;
    int r = blockIdx.x * 4 + w;
    if (r >= N) return;
    const uint32* su = (const uint32*)supb;

    float a0 = 0.f, a1 = 0.f, k0 = 0.f, k1 = 0.f;
    {
        int e = rp_a[r], e1 = rp_a[r + 1];
        for (; e + 2 <= e1; e += 2) {
            int c0 = scol_a[e], c1 = scol_a[e + 1];
            float v0 = sval_a[e], v1 = sval_a[e + 1];
            uint32 u0 = su[(size_t)c0 * 64 + lane];
            uint32 u1 = su[(size_t)c1 * 64 + lane];
            a0 += v0 * bflo(u0) + v1 * bflo(u1);
            a1 += v0 * bfhi(u0) + v1 * bfhi(u1);
        }
        if (e < e1) {
            uint32 u0 = su[(size_t)scol_a[e] * 64 + lane];
            float v0 = sval_a[e];
            a0 += v0 * bflo(u0); a1 += v0 * bfhi(u0);
        }
    }
    {
        int e = rp_k[r], e1 = rp_k[r + 1];
        for (; e + 2 <= e1; e += 2) {
            int c0 = scol_k[e], c1 = scol_k[e + 1];
            float v0 = sval_k[e], v1 = sval_k[e + 1];
            uint32 u0 = su[(size_t)c0 * 64 + lane];
            uint32 u1 = su[(size_t)c1 * 64 + lane];
            k0 += v0 * bflo(u0) + v1 * bflo(u1);
            k1 += v0 * bfhi(u0) + v1 * bfhi(u1);
        }
        if (e < e1) {
            uint32 u0 = su[(size_t)scol_k[e] * 64 + lane];
            float v0 = sval_k[e];
            k0 += v0 * bflo(u0); k1 += v0 * bfhi(u0);
        }
    }

    float si = s[r];
    float g = GAMMA * dk[r];
    uint32 ui = su[(size_t)r * 64 + lane];
    int c0i = lane * 2, c1i = lane * 2 + 1;
    float o0 = si * a0 + (1.f - si) * k0 + g * bflo(ui) + b1[c0i] * (1.f + g);
    float o1 = si * a1 + (1.f - si) * k1 + g * bfhi(ui) + b1[c1i] * (1.f + g);

    *reinterpret_cast<float2*>(emb + (size_t)r * 128 + c0i) = make_float2(o0, o1);
    ((uint32*)embb)[(size_t)r * 64 + lane] = pack2bf(o0, o1);

    float as = o0 * s2w[c0i] + o1 * s2w[c1i];
    float ad = o0 * d2w[c0i] + o1 * d2w[c1i];
    #pragma unroll
    for (int off = 32; off; off >>= 1) {
        as += __shfl_xor(as, off);
        ad += __shfl_xor(ad, off);
    }
    if (lane == 0) {
        s_out[r] = 1.f / (1.f + __expf(-(as + s2b[0])));
        dk_out[r] = ad + d2b[0];
    }
}

// ---------- fused SPMM x2 + combine + log_softmax layer2 ----------
__global__ __launch_bounds__(256) void spmm_combine2_lsm(
    const int* __restrict__ rp_a, const int* __restrict__ scol_a, const float* __restrict__ sval_a,
    const int* __restrict__ rp_k, const int* __restrict__ scol_k, const float* __restrict__ sval_k,
    const ushort16* __restrict__ supb, const float* __restrict__ supf,
    const float* __restrict__ s, const float* __restrict__ dk,
    const float* __restrict__ b2, float* __restrict__ out, int N) {
    int w = threadIdx.x >> 6, lane = threadIdx.x & 63;
    int r = blockIdx.x * 4 + w;
    if (r >= N) return;
    int g = lane >> 5, li = lane & 31;
    bool act = li < 20;
    const uint32* su = (const uint32*)supb;

    float a0 = 0.f, a1 = 0.f, k0 = 0.f, k1 = 0.f;
    {
        int e1 = rp_a[r + 1];
        for (int e = rp_a[r] + g; e < e1; e += 2) {
            int c = scol_a[e];
            float v = sval_a[e];
            if (act) {
                uint32 u = su[(size_t)c * 20 + li];
                a0 += v * bflo(u); a1 += v * bfhi(u);
            }
        }
    }
    {
        int e1 = rp_k[r + 1];
        for (int e = rp_k[r] + g; e < e1; e += 2) {
            int c = scol_k[e];
            float v = sval_k[e];
            if (act) {
                uint32 u = su[(size_t)c * 20 + li];
                k0 += v * bflo(u); k1 += v * bfhi(u);
            }
        }
    }
    a0 += __shfl_xor(a0, 32); a1 += __shfl_xor(a1, 32);
    k0 += __shfl_xor(k0, 32); k1 += __shfl_xor(k1, 32);

    float si = s[r];
    float gg = GAMMA * dk[r];
    float z0 = -INFINITY, z1 = -INFINITY;
    bool lead = act && (lane < 32);
    if (lead) {
        float2 iv = *reinterpret_cast<const float2*>(supf + (size_t)r * 40 + li * 2);
        z0 = si * a0 + (1.f - si) * k0 + gg * iv.x + b2[li * 2] * (1.f + gg);
        z1 = si * a1 + (1.f - si) * k1 + gg * iv.y + b2[li * 2 + 1] * (1.f + gg);
    }
    float m = fmaxf(z0, z1);
    #pragma unroll
    for (int off = 16; off; off >>= 1) m = fmaxf(m, __shfl_xor(m, off));
    float ex = lead ? (__expf(z0 - m) + __expf(z1 - m)) : 0.f;
    #pragma unroll
    for (int off = 16; off; off >>= 1) ex += __shfl_xor(ex, off);
    float lse = m + __logf(ex);
    if (lead)
        *reinterpret_cast<float2*>(out + (size_t)r * 40 + li * 2) = make_float2(z0 - lse, z1 - lse);
}

static inline size_t align256(size_t x) { return (x + 255) & ~(size_t)255; }

extern "C" void kernel_launch(void* const* d_in, const int* in_sizes, int n_in,
                              void* d_out, int out_size, void* d_ws, size_t ws_size,
                              hipStream_t stream) {
    const int N = 50000, C = 40;

    const float* fea     = (const float*)d_in[0];
    const int*   adj_row = (const int*)d_in[1];
    const int*   adj_col = (const int*)d_in[2];
    const float* adj_val = (const float*)d_in[3];
    const int*   knn_row = (const int*)d_in[4];
    const int*   knn_col = (const int*)d_in[5];
    const float* knn_val = (const float*)d_in[6];
    const float* W1      = (const float*)d_in[7];
    const float* b1      = (const float*)d_in[8];
    const float* W2      = (const float*)d_in[9];
    const float* b2      = (const float*)d_in[10];
    const float* score1  = (const float*)d_in[11];
    const float* score2  = (const float*)d_in[12];
    const float* sbias1  = (const float*)d_in[13];
    const float* sbias2  = (const float*)d_in[14];
    const float* Dk1     = (const float*)d_in[15];
    const float* Dk2     = (const float*)d_in[16];
    const float* Dbias1  = (const float*)d_in[17];
    const float* Dbias2  = (const float*)d_in[18];

    const int E  = in_sizes[1];
    const int EK = in_sizes[4];

    float* out_lsm = (float*)d_out;
    float* emb     = out_lsm + (size_t)N * C;

    // workspace carve
    char* wp = (char*)d_ws;
    ushort16* W1bt = (ushort16*)wp; wp += align256((size_t)128 * 512 * 2);
    ushort16* W2bt = (ushort16*)wp; wp += align256((size_t)48 * 128 * 2);
    ushort16* sup1b = (ushort16*)wp; wp += align256((size_t)N * 128 * 2);
    ushort16* embb  = (ushort16*)wp; wp += align256((size_t)N * 128 * 2);
    float* sup2     = (float*)wp;   wp += align256((size_t)N * 40 * 4);
    ushort16* sup2b = (ushort16*)wp; wp += align256((size_t)N * 40 * 2);
    float* s_buf  = (float*)wp; wp += align256((size_t)N * 4);
    float* dk_buf = (float*)wp; wp += align256((size_t)N * 4);
    int* rp_a = (int*)wp; wp += align256((size_t)(N + 1) * 4);
    int* rp_k = (int*)wp; wp += align256((size_t)(N + 1) * 4);
    int* cnt  = (int*)wp; wp += align256((size_t)2 * N * 4);
    int* partial = (int*)wp; wp += align256((size_t)256 * 4);
    int* scol_a   = (int*)wp;   wp += align256((size_t)E * 4);
    float* sval_a = (float*)wp; wp += align256((size_t)E * 4);
    int* scol_k   = (int*)wp;   wp += align256((size_t)EK * 4);
    float* sval_k = (float*)wp; wp += align256((size_t)EK * 4);

    int egrid = (max(E, EK) + 255) / 256;
    int mgrid = (N + 63) / 64;
    int NB = (N + SEG - 1) / SEG;   // 13

    // prep + CSR build
    prep_wt<<<256, 256, 0, stream>>>(W1, W2, W1bt, W2bt);
    hipMemsetAsync(cnt, 0, (size_t)2 * N * 4, stream);
    hist2<<<egrid, 256, 0, stream>>>(adj_row, E, knn_row, EK, cnt, N);
    scan_partial<<<2 * NB, 256, 0, stream>>>(cnt, partial, N, NB);
    scan_offsets<<<1, 64, 0, stream>>>(partial, NB, rp_a, rp_k, N);
    scan_final<<<2 * NB, 256, 0, stream>>>(cnt, partial, rp_a, rp_k, N, NB);
    scatter2<<<egrid, 256, 0, stream>>>(adj_row, adj_col, adj_val, E,
                                        knn_row, knn_col, knn_val, EK,
                                        cnt, N,
                                        scol_a, sval_a, scol_k, sval_k);

    // layer 1
    gemm1_mfma<<<mgrid, 256, 0, stream>>>(fea, W1bt, score1, Dk1, sbias1, Dbias1,
                                          sup1b, s_buf, dk_buf, N);
    spmm_combine1<<<(N + 3) / 4, 256, 0, stream>>>(rp_a, scol_a, sval_a,
                                                   rp_k, scol_k, sval_k,
                                                   sup1b, s_buf, dk_buf, b1,
                                                   score2, Dk2, sbias2, Dbias2,
                                                   emb, embb, s_buf, dk_buf, N);

    // layer 2
    gemm2_mfma<<<mgrid, 256, 0, stream>>>(embb, W2bt, sup2, sup2b, N);
    spmm_combine2_lsm<<<(N + 3) / 4, 256, 0, stream>>>(rp_a, scol_a, sval_a,
                                                       rp_k, scol_k, sval_k,
                                                       sup2b, sup2, s_buf, dk_buf,
                                                       b2, out_lsm, N);

    (void)n_in; (void)out_size; (void)ws_size;
}

// Round 6
// 537.976 us; speedup vs baseline: 2.7792x; 1.2518x over previous
//
#include <hip/hip_runtime.h>
#include <hip/hip_bf16.h>
#include <cstdint>

#define GAMMA 0.1f
#define CAP 64
#define OVF_CAP 8192

typedef unsigned int  uint32;
typedef unsigned short ushort16;
typedef float f32x4 __attribute__((ext_vector_type(4)));
typedef __bf16 bf16x8 __attribute__((ext_vector_type(8)));

union U16x8 { uint4 u4; bf16x8 bv; };

static __device__ __forceinline__ ushort16 f2bf(float f) {
    union { float f; uint32 u; } x; x.f = f;
    uint32 r = (x.u + 0x7FFFu + ((x.u >> 16) & 1u)) >> 16;
    return (ushort16)r;
}
static __device__ __forceinline__ uint32 pack2bf(float lo, float hi) {
    return (uint32)f2bf(lo) | ((uint32)f2bf(hi) << 16);
}
static __device__ __forceinline__ float bflo(uint32 u) { return __uint_as_float(u << 16); }
static __device__ __forceinline__ float bfhi(uint32 u) { return __uint_as_float(u & 0xFFFF0000u); }

// ---------- prep: W1^T, W2^T (bf16, W2 padded to 48 cols) ----------
__global__ __launch_bounds__(256) void prep_wt(const float* __restrict__ W1,
                                               const float* __restrict__ W2,
                                               ushort16* __restrict__ W1bt,
                                               ushort16* __restrict__ W2bt) {
    int t = blockIdx.x * 256 + threadIdx.x;
    if (t < 128 * 512) { int c = t >> 9, k = t & 511; W1bt[t] = f2bf(W1[k * 128 + c]); }
    if (t < 48 * 128)  { int c = t >> 7, k = t & 127; W2bt[t] = f2bf(c < 40 ? W2[k * 40 + c] : 0.f); }
}

// ---------- fused: GEMM1 (blocks [0,mgrid)) + bucket-scatter (rest) ----------
// GEMM1: sup1b[M,128](bf16) = fea[M,512] @ W1, fused s/Dk gates.
// Scatter: packed_x[r*CAP + cursor] = (col<<16)|bf16(val); overflow -> side list.
__global__ __launch_bounds__(256) void gemm1_scatter(
    const float* __restrict__ A, const ushort16* __restrict__ Bt,
    const float* __restrict__ s1w, const float* __restrict__ d1w,
    const float* __restrict__ s1b, const float* __restrict__ d1b,
    ushort16* __restrict__ Cb, float* __restrict__ s_out, float* __restrict__ dk_out,
    int M, int mgrid,
    const int* __restrict__ arow_, const int* __restrict__ acol_, const float* __restrict__ aval_, int E,
    const int* __restrict__ krow_, const int* __restrict__ kcol_, const float* __restrict__ kval_, int EK,
    int* __restrict__ cnt, int N,
    uint32* __restrict__ packed_a, uint32* __restrict__ packed_k,
    uint2* __restrict__ ovf_a, uint2* __restrict__ ovf_k) {
    int bid = blockIdx.x;
    if (bid >= mgrid) {
        // ---------------- scatter path ----------------
        int i = (bid - mgrid) * 256 + threadIdx.x;
        if (i < E) {
            int r = arow_[i];
            uint32 rec = ((uint32)acol_[i] << 16) | (uint32)f2bf(aval_[i]);
            int p = atomicAdd(&cnt[r], 1);
            if (p < CAP) packed_a[(size_t)r * CAP + p] = rec;
            else { int q = atomicAdd(&cnt[2 * N], 1); if (q < OVF_CAP) ovf_a[q] = make_uint2((uint32)r, rec); }
        }
        if (i < EK) {
            int r = krow_[i];
            uint32 rec = ((uint32)kcol_[i] << 16) | (uint32)f2bf(kval_[i]);
            int p = atomicAdd(&cnt[N + r], 1);
            if (p < CAP) packed_k[(size_t)r * CAP + p] = rec;
            else { int q = atomicAdd(&cnt[2 * N + 1], 1); if (q < OVF_CAP) ovf_k[q] = make_uint2((uint32)r, rec); }
        }
        return;
    }
    // ---------------- GEMM1 path ----------------
    int w = threadIdx.x >> 6, lane = threadIdx.x & 63;
    int row16 = lane & 15, kc = lane >> 4;
    int wrow0 = bid * 64 + w * 16;
    int r = wrow0 + row16;
    int rc = min(r, M - 1);
    const float* arow = A + (size_t)rc * 512;

    f32x4 acc[8];
    #pragma unroll
    for (int c = 0; c < 8; ++c) acc[c] = (f32x4){0.f, 0.f, 0.f, 0.f};
    float sdot = 0.f, ddot = 0.f;

    for (int ks = 0; ks < 16; ++ks) {
        int kb = ks * 32 + kc * 8;
        float4 a0 = *reinterpret_cast<const float4*>(arow + kb);
        float4 a1 = *reinterpret_cast<const float4*>(arow + kb + 4);
        float4 sw0 = *reinterpret_cast<const float4*>(s1w + kb);
        float4 sw1 = *reinterpret_cast<const float4*>(s1w + kb + 4);
        float4 dw0 = *reinterpret_cast<const float4*>(d1w + kb);
        float4 dw1 = *reinterpret_cast<const float4*>(d1w + kb + 4);
        sdot += a0.x * sw0.x + a0.y * sw0.y + a0.z * sw0.z + a0.w * sw0.w +
                a1.x * sw1.x + a1.y * sw1.y + a1.z * sw1.z + a1.w * sw1.w;
        ddot += a0.x * dw0.x + a0.y * dw0.y + a0.z * dw0.z + a0.w * dw0.w +
                a1.x * dw1.x + a1.y * dw1.y + a1.z * dw1.z + a1.w * dw1.w;
        U16x8 ua;
        ua.u4 = make_uint4(pack2bf(a0.x, a0.y), pack2bf(a0.z, a0.w),
                           pack2bf(a1.x, a1.y), pack2bf(a1.z, a1.w));
        #pragma unroll
        for (int c = 0; c < 8; ++c) {
            U16x8 ub;
            ub.u4 = *reinterpret_cast<const uint4*>(Bt + (size_t)(c * 16 + row16) * 512 + kb);
            acc[c] = __builtin_amdgcn_mfma_f32_16x16x32_bf16(ua.bv, ub.bv, acc[c], 0, 0, 0);
        }
    }

    sdot += __shfl_xor(sdot, 16); sdot += __shfl_xor(sdot, 32);
    ddot += __shfl_xor(ddot, 16); ddot += __shfl_xor(ddot, 32);
    if (kc == 0 && r < M) {
        s_out[r] = 1.f / (1.f + __expf(-(sdot + s1b[0])));
        dk_out[r] = ddot + d1b[0];
    }

    #pragma unroll
    for (int c = 0; c < 8; ++c) {
        #pragma unroll
        for (int i = 0; i < 4; ++i) {
            int orow = wrow0 + (lane >> 4) * 4 + i;
            if (orow < M) Cb[(size_t)orow * 128 + c * 16 + row16] = f2bf(acc[c][i]);
        }
    }
}

// ---------- GEMM2: sup2[M,40](f32)+sup2b(bf16) = embb[M,128](bf16) @ W2 ----------
__global__ __launch_bounds__(256) void gemm2_mfma(const ushort16* __restrict__ Ab,
                                                  const ushort16* __restrict__ Bt,
                                                  float* __restrict__ C,
                                                  ushort16* __restrict__ Cb,
                                                  int M) {
    int w = threadIdx.x >> 6, lane = threadIdx.x & 63;
    int row16 = lane & 15, kc = lane >> 4;
    int wrow0 = blockIdx.x * 64 + w * 16;
    int r = wrow0 + row16;
    int rc = min(r, M - 1);

    f32x4 acc[3];
    #pragma unroll
    for (int c = 0; c < 3; ++c) acc[c] = (f32x4){0.f, 0.f, 0.f, 0.f};

    #pragma unroll
    for (int ks = 0; ks < 4; ++ks) {
        int kb = ks * 32 + kc * 8;
        U16x8 ua;
        ua.u4 = *reinterpret_cast<const uint4*>(Ab + (size_t)rc * 128 + kb);
        #pragma unroll
        for (int c = 0; c < 3; ++c) {
            U16x8 ub;
            ub.u4 = *reinterpret_cast<const uint4*>(Bt + (size_t)(c * 16 + row16) * 128 + kb);
            acc[c] = __builtin_amdgcn_mfma_f32_16x16x32_bf16(ua.bv, ub.bv, acc[c], 0, 0, 0);
        }
    }

    #pragma unroll
    for (int c = 0; c < 3; ++c) {
        int col = c * 16 + row16;
        #pragma unroll
        for (int i = 0; i < 4; ++i) {
            int orow = wrow0 + (lane >> 4) * 4 + i;
            if (orow < M && col < 40) {
                C[(size_t)orow * 40 + col] = acc[c][i];
                Cb[(size_t)orow * 40 + col] = f2bf(acc[c][i]);
            }
        }
    }
}

// ---------- fused SPMM(adj)+SPMM(knn)+combine layer1 + layer2 gates ----------
__global__ __launch_bounds__(256) void spmm_combine1(
    const int* __restrict__ cnt,
    const uint32* __restrict__ packed_a, const uint32* __restrict__ packed_k,
    const uint2* __restrict__ ovf_a, const uint2* __restrict__ ovf_k,
    const ushort16* __restrict__ supb, const float* __restrict__ s, const float* __restrict__ dk,
    const float* __restrict__ b1,
    const float* __restrict__ s2w, const float* __restrict__ d2w,
    const float* __restrict__ s2b, const float* __restrict__ d2b,
    float* __restrict__ emb, ushort16* __restrict__ embb,
    float* __restrict__ s_out, float* __restrict__ dk_out, int N) {
    int w = threadIdx.x >> 6, lane = threadIdx.x & 63;
    int r = blockIdx.x * 4 + w;
    if (r >= N) return;
    const uint32* su = (const uint32*)supb;

    float a0 = 0.f, a1 = 0.f, k0 = 0.f, k1 = 0.f;
    {
        const uint32* pa = packed_a + (size_t)r * CAP;
        int d = min(cnt[r], CAP);
        int e = 0;
        for (; e + 2 <= d; e += 2) {
            uint32 r0 = pa[e], r1 = pa[e + 1];
            float v0 = bflo(r0), v1 = bflo(r1);
            uint32 u0 = su[((size_t)(r0 >> 16) << 6) + lane];
            uint32 u1 = su[((size_t)(r1 >> 16) << 6) + lane];
            a0 += v0 * bflo(u0) + v1 * bflo(u1);
            a1 += v0 * bfhi(u0) + v1 * bfhi(u1);
        }
        if (e < d) {
            uint32 r0 = pa[e];
            float v0 = bflo(r0);
            uint32 u0 = su[((size_t)(r0 >> 16) << 6) + lane];
            a0 += v0 * bflo(u0); a1 += v0 * bfhi(u0);
        }
    }
    {
        const uint32* pk = packed_k + (size_t)r * CAP;
        int d = min(cnt[N + r], CAP);
        int e = 0;
        for (; e + 2 <= d; e += 2) {
            uint32 r0 = pk[e], r1 = pk[e + 1];
            float v0 = bflo(r0), v1 = bflo(r1);
            uint32 u0 = su[((size_t)(r0 >> 16) << 6) + lane];
            uint32 u1 = su[((size_t)(r1 >> 16) << 6) + lane];
            k0 += v0 * bflo(u0) + v1 * bflo(u1);
            k1 += v0 * bfhi(u0) + v1 * bfhi(u1);
        }
        if (e < d) {
            uint32 r0 = pk[e];
            float v0 = bflo(r0);
            uint32 u0 = su[((size_t)(r0 >> 16) << 6) + lane];
            k0 += v0 * bflo(u0); k1 += v0 * bfhi(u0);
        }
    }
    // overflow (normally empty)
    int nova = min(cnt[2 * N], OVF_CAP);
    for (int i = 0; i < nova; ++i) {
        uint2 t = ovf_a[i];
        if ((int)t.x == r) {
            float v = bflo(t.y);
            uint32 u = su[((size_t)(t.y >> 16) << 6) + lane];
            a0 += v * bflo(u); a1 += v * bfhi(u);
        }
    }
    int novk = min(cnt[2 * N + 1], OVF_CAP);
    for (int i = 0; i < novk; ++i) {
        uint2 t = ovf_k[i];
        if ((int)t.x == r) {
            float v = bflo(t.y);
            uint32 u = su[((size_t)(t.y >> 16) << 6) + lane];
            k0 += v * bflo(u); k1 += v * bfhi(u);
        }
    }

    float si = s[r];
    float g = GAMMA * dk[r];
    uint32 ui = su[((size_t)r << 6) + lane];
    int c0i = lane * 2, c1i = lane * 2 + 1;
    float o0 = si * a0 + (1.f - si) * k0 + g * bflo(ui) + b1[c0i] * (1.f + g);
    float o1 = si * a1 + (1.f - si) * k1 + g * bfhi(ui) + b1[c1i] * (1.f + g);

    *reinterpret_cast<float2*>(emb + (size_t)r * 128 + c0i) = make_float2(o0, o1);
    ((uint32*)embb)[((size_t)r << 6) + lane] = pack2bf(o0, o1);

    float as = o0 * s2w[c0i] + o1 * s2w[c1i];
    float ad = o0 * d2w[c0i] + o1 * d2w[c1i];
    #pragma unroll
    for (int off = 32; off; off >>= 1) {
        as += __shfl_xor(as, off);
        ad += __shfl_xor(ad, off);
    }
    if (lane == 0) {
        s_out[r] = 1.f / (1.f + __expf(-(as + s2b[0])));
        dk_out[r] = ad + d2b[0];
    }
}

// ---------- fused SPMM x2 + combine + log_softmax layer2 ----------
__global__ __launch_bounds__(256) void spmm_combine2_lsm(
    const int* __restrict__ cnt,
    const uint32* __restrict__ packed_a, const uint32* __restrict__ packed_k,
    const uint2* __restrict__ ovf_a, const uint2* __restrict__ ovf_k,
    const ushort16* __restrict__ supb, const float* __restrict__ supf,
    const float* __restrict__ s, const float* __restrict__ dk,
    const float* __restrict__ b2, float* __restrict__ out, int N) {
    int w = threadIdx.x >> 6, lane = threadIdx.x & 63;
    int r = blockIdx.x * 4 + w;
    if (r >= N) return;
    int g = lane >> 5, li = lane & 31;
    bool act = li < 20;
    const uint32* su = (const uint32*)supb;

    float a0 = 0.f, a1 = 0.f, k0 = 0.f, k1 = 0.f;
    {
        const uint32* pa = packed_a + (size_t)r * CAP;
        int d = min(cnt[r], CAP);
        for (int e = g; e < d; e += 2) {
            uint32 rec = pa[e];
            float v = bflo(rec);
            if (act) {
                uint32 u = su[(size_t)(rec >> 16) * 20 + li];
                a0 += v * bflo(u); a1 += v * bfhi(u);
            }
        }
    }
    {
        const uint32* pk = packed_k + (size_t)r * CAP;
        int d = min(cnt[N + r], CAP);
        for (int e = g; e < d; e += 2) {
            uint32 rec = pk[e];
            float v = bflo(rec);
            if (act) {
                uint32 u = su[(size_t)(rec >> 16) * 20 + li];
                k0 += v * bflo(u); k1 += v * bfhi(u);
            }
        }
    }
    // overflow (normally empty) — group 0 only to avoid double count
    int nova = min(cnt[2 * N], OVF_CAP);
    for (int i = 0; i < nova; ++i) {
        uint2 t = ovf_a[i];
        if ((int)t.x == r && g == 0 && act) {
            float v = bflo(t.y);
            uint32 u = su[(size_t)(t.y >> 16) * 20 + li];
            a0 += v * bflo(u); a1 += v * bfhi(u);
        }
    }
    int novk = min(cnt[2 * N + 1], OVF_CAP);
    for (int i = 0; i < novk; ++i) {
        uint2 t = ovf_k[i];
        if ((int)t.x == r && g == 0 && act) {
            float v = bflo(t.y);
            uint32 u = su[(size_t)(t.y >> 16) * 20 + li];
            k0 += v * bflo(u); k1 += v * bfhi(u);
        }
    }
    a0 += __shfl_xor(a0, 32); a1 += __shfl_xor(a1, 32);
    k0 += __shfl_xor(k0, 32); k1 += __shfl_xor(k1, 32);

    float si = s[r];
    float gg = GAMMA * dk[r];
    float z0 = -INFINITY, z1 = -INFINITY;
    bool lead = act && (lane < 32);
    if (lead) {
        float2 iv = *reinterpret_cast<const float2*>(supf + (size_t)r * 40 + li * 2);
        z0 = si * a0 + (1.f - si) * k0 + gg * iv.x + b2[li * 2] * (1.f + gg);
        z1 = si * a1 + (1.f - si) * k1 + gg * iv.y + b2[li * 2 + 1] * (1.f + gg);
    }
    float m = fmaxf(z0, z1);
    #pragma unroll
    for (int off = 16; off; off >>= 1) m = fmaxf(m, __shfl_xor(m, off));
    float ex = lead ? (__expf(z0 - m) + __expf(z1 - m)) : 0.f;
    #pragma unroll
    for (int off = 16; off; off >>= 1) ex += __shfl_xor(ex, off);
    float lse = m + __logf(ex);
    if (lead)
        *reinterpret_cast<float2*>(out + (size_t)r * 40 + li * 2) = make_float2(z0 - lse, z1 - lse);
}

static inline size_t align256(size_t x) { return (x + 255) & ~(size_t)255; }

extern "C" void kernel_launch(void* const* d_in, const int* in_sizes, int n_in,
                              void* d_out, int out_size, void* d_ws, size_t ws_size,
                              hipStream_t stream) {
    const int N = 50000, C = 40;

    const float* fea     = (const float*)d_in[0];
    const int*   adj_row = (const int*)d_in[1];
    const int*   adj_col = (const int*)d_in[2];
    const float* adj_val = (const float*)d_in[3];
    const int*   knn_row = (const int*)d_in[4];
    const int*   knn_col = (const int*)d_in[5];
    const float* knn_val = (const float*)d_in[6];
    const float* W1      = (const float*)d_in[7];
    const float* b1      = (const float*)d_in[8];
    const float* W2      = (const float*)d_in[9];
    const float* b2      = (const float*)d_in[10];
    const float* score1  = (const float*)d_in[11];
    const float* score2  = (const float*)d_in[12];
    const float* sbias1  = (const float*)d_in[13];
    const float* sbias2  = (const float*)d_in[14];
    const float* Dk1     = (const float*)d_in[15];
    const float* Dk2     = (const float*)d_in[16];
    const float* Dbias1  = (const float*)d_in[17];
    const float* Dbias2  = (const float*)d_in[18];

    const int E  = in_sizes[1];
    const int EK = in_sizes[4];

    float* out_lsm = (float*)d_out;
    float* emb     = out_lsm + (size_t)N * C;

    // workspace carve (~52 MB). sup2/sup2b overlay sup1b (dead after spmm_combine1).
    char* wp = (char*)d_ws;
    ushort16* W1bt = (ushort16*)wp; wp += align256((size_t)128 * 512 * 2);
    ushort16* W2bt = (ushort16*)wp; wp += align256((size_t)48 * 128 * 2);
    char* sup1_region = wp;          wp += align256((size_t)N * 128 * 2);   // 12.8 MB
    ushort16* sup1b = (ushort16*)sup1_region;
    float* sup2     = (float*)sup1_region;                                   // N*40*4 = 8 MB
    ushort16* sup2b = (ushort16*)(sup1_region + (size_t)N * 40 * 4);         // +4 MB = 12 MB <= 12.8
    ushort16* embb  = (ushort16*)wp; wp += align256((size_t)N * 128 * 2);
    float* s_buf  = (float*)wp; wp += align256((size_t)N * 4);
    float* dk_buf = (float*)wp; wp += align256((size_t)N * 4);
    int* cnt  = (int*)wp; wp += align256((size_t)(2 * N + 2) * 4);
    uint32* packed_a = (uint32*)wp; wp += align256((size_t)N * CAP * 4);
    uint32* packed_k = (uint32*)wp; wp += align256((size_t)N * CAP * 4);
    uint2* ovf_a = (uint2*)wp; wp += align256((size_t)OVF_CAP * 8);
    uint2* ovf_k = (uint2*)wp; wp += align256((size_t)OVF_CAP * 8);

    int egrid = (max(E, EK) + 255) / 256;
    int mgrid = (N + 63) / 64;

    prep_wt<<<256, 256, 0, stream>>>(W1, W2, W1bt, W2bt);
    hipMemsetAsync(cnt, 0, (size_t)(2 * N + 2) * 4, stream);

    // fused GEMM1 + bucket scatter (independent work, co-scheduled)
    gemm1_scatter<<<mgrid + egrid, 256, 0, stream>>>(
        fea, W1bt, score1, Dk1, sbias1, Dbias1, sup1b, s_buf, dk_buf, N, mgrid,
        adj_row, adj_col, adj_val, E, knn_row, knn_col, knn_val, EK,
        cnt, N, packed_a, packed_k, ovf_a, ovf_k);

    spmm_combine1<<<(N + 3) / 4, 256, 0, stream>>>(cnt, packed_a, packed_k, ovf_a, ovf_k,
                                                   sup1b, s_buf, dk_buf, b1,
                                                   score2, Dk2, sbias2, Dbias2,
                                                   emb, embb, s_buf, dk_buf, N);

    gemm2_mfma<<<mgrid, 256, 0, stream>>>(embb, W2bt, sup2, sup2b, N);

    spmm_combine2_lsm<<<(N + 3) / 4, 256, 0, stream>>>(cnt, packed_a, packed_k, ovf_a, ovf_k,
                                                       sup2b, sup2, s_buf, dk_buf,
                                                       b2, out_lsm, N);

    (void)n_in; (void)out_size; (void)ws_size;
}